// Round 6
// baseline (306.109 us; speedup 1.0000x reference)
//
#include <hip/hip_runtime.h>
#include <hip/hip_bf16.h>
#include <math.h>

#define NTOT 16384
#define HDIM 256
#define BBATCH 4
#define NSEQ 4096
#define FDIM 256
#define NE 262144
#define NEE (NE + NTOT)
#define NLAYER 3
#define LN_EPS 1e-5f
#define SLOPE 0.2f

typedef __attribute__((ext_vector_type(8))) short bf16x8;
typedef __attribute__((ext_vector_type(4))) float f32x4;

#define LDW 80   // LDS row stride in bytes (64B payload + 16B pad -> 2-way bank alias, free)

// ---- workspace layout (bytes) ----
#define OFF_HA   0u          // ushort[NTOT*256]  8388608   node features (bf16)
#define OFF_HW   8388608u    // ushort[NTOT*256]  8388608   hw = h@W (bf16)
#define OFF_XB   16777216u   // ushort[NTOT*256]  8388608   x in bf16
#define OFF_WC   25165824u   // ushort[256*768]   393216    conv weight^T bf16, k = tap*256+f
#define OFF_WL   25559040u   // ushort[3*256*256] 393216    layer W^T bf16
#define OFF_SP   25952256u   // float[4*NTOT]     262144    s partials (per col-block)
#define OFF_DP   26214400u   // float[4*NTOT]     262144    d partials
#define OFF_CNT  26476544u   // int[NTOT]
#define OFF_OFF  26542080u   // int[NTOT+1] (pad 65792)
#define OFF_CUR  26607872u   // int[NTOT]
#define OFF_CSR  26673408u   // int[NEE] 1114112
#define OFF_WT   27787520u   // float[3*256*256]  786432   fp32 conv weight^T for k_final
#define OFF_SV   28573952u   // float[NTOT]       65536    s summed
#define OFF_DV   28639488u   // float[NTOT]       65536    d summed
#define OFF_CTR  28705024u   // int[128]          512      strip completion counters
// total ~28.7 MB

static __device__ __forceinline__ unsigned short f2b(float f) {
    __hip_bfloat16 h = __float2bfloat16(f);
    return __builtin_bit_cast(unsigned short, h);
}
static __device__ __forceinline__ float b2f(unsigned short u) {
    __hip_bfloat16 h = __builtin_bit_cast(__hip_bfloat16, u);
    return __bfloat162float(h);
}
static __device__ __forceinline__ float rlanef(float v, int l) {
    return __builtin_bit_cast(float, __builtin_amdgcn_readlane(__builtin_bit_cast(int, v), l));
}

// ---- merged pre-pass: x->bf16 (+zero cnt/ctr), weight prep ----
// grid: [0,4096) xbf ; [4096,5888) prep.  (count is a SEPARATE kernel: stream
// ordering guarantees cnt is zeroed before any atomicAdd — same-dispatch
// zero+count raced and crashed in round 4.)
__global__ __launch_bounds__(256) void k_pre(const float* __restrict__ x, unsigned short* __restrict__ xb,
                                             int* __restrict__ cnt, int* __restrict__ ctr,
                                             const float* __restrict__ tcw, const float* __restrict__ gatW,
                                             unsigned short* __restrict__ wcB, unsigned short* __restrict__ WTb,
                                             float* __restrict__ wT) {
    int b = blockIdx.x, t = threadIdx.x;
    if (b < 4096) {
        int i = (b * 256 + t) * 4;
        float4 v = *(const float4*)(x + i);
        ushort4 o;
        o.x = f2b(v.x); o.y = f2b(v.y); o.z = f2b(v.z); o.w = f2b(v.w);
        *(ushort4*)(xb + i) = o;
        if (b < 16) *(int4*)(cnt + i) = make_int4(0, 0, 0, 0);   // 16*256*4 = 16384 ints, aligned
        if (b == 16 && t < 128) ctr[t] = 0;
    } else {
        int bb = b - 4096;
        if (bb < 256) {
            const float* s = tcw + bb * 768 + t * 3;
            wcB[bb * 768 + 0 + t]   = f2b(s[0]);
            wcB[bb * 768 + 256 + t] = f2b(s[1]);
            wcB[bb * 768 + 512 + t] = f2b(s[2]);
        } else if (bb < 1024) {
            int ln = bb - 256; int n = ln & 255; int l = ln >> 8;
            WTb[(size_t)l * 65536 + n * 256 + t] = f2b(gatW[(size_t)l * 65536 + t * 256 + n]);
        } else {
            int fk = bb - 1024; int f = fk / 3, k = fk - 3 * f;
            wT[(k * FDIM + f) * HDIM + t] = tcw[t * 768 + fk];
        }
    }
}

__global__ __launch_bounds__(256) void k_count(const int* __restrict__ ei, int* __restrict__ cnt) {
    int e = blockIdx.x * 256 + threadIdx.x;
    int dst = (e < NE) ? ei[NE + e] : (e - NE);
    atomicAdd(&cnt[dst], 1);
}

__global__ __launch_bounds__(1024) void k_scan(const int* __restrict__ cnt, int* __restrict__ off,
                                               int* __restrict__ cur) {
    __shared__ int sums[1024];
    int t = threadIdx.x;
    int base = t * 16;
    int c[16]; int s = 0;
    #pragma unroll
    for (int j = 0; j < 16; ++j) { c[j] = cnt[base + j]; s += c[j]; }
    sums[t] = s;
    __syncthreads();
    for (int dstep = 1; dstep < 1024; dstep <<= 1) {
        int v = (t >= dstep) ? sums[t - dstep] : 0;
        __syncthreads();
        sums[t] += v;
        __syncthreads();
    }
    int pre = (t == 0) ? 0 : sums[t - 1];
    #pragma unroll
    for (int j = 0; j < 16; ++j) { off[base + j] = pre; cur[base + j] = pre; pre += c[j]; }
    if (t == 1023) off[NTOT] = pre;
}

// ---- merged: CSR scatter [0,1088) + conv GEMM [1088,1600) ----
__global__ __launch_bounds__(256) void k_scat_conv(const int* __restrict__ ei, int* __restrict__ cur,
                                                   int* __restrict__ csr,
                                                   const unsigned short* __restrict__ xbf,
                                                   const float* __restrict__ x,
                                                   const unsigned short* __restrict__ wcB,
                                                   const float* __restrict__ tcb,
                                                   unsigned short* __restrict__ hAb) {
    __shared__ char lds[128 * LDW + 64 * LDW];
    int t = threadIdx.x;
    if (blockIdx.x < 1088) {
        int e = blockIdx.x * 256 + t;
        int src, dst;
        if (e < NE) { src = ei[e]; dst = ei[NE + e]; } else { src = dst = e - NE; }
        int pos = atomicAdd(&cur[dst], 1);
        csr[pos] = src;
        return;
    }
    int blk = blockIdx.x - 1088;
    char* As = lds;
    char* Bs = lds + 128 * LDW;
    int m0 = (blk & 127) * 128, n0 = (blk >> 7) * 64;
    int bb = m0 >> 12;
    int nloc0 = m0 & 4095;
    int w = t >> 6, lane = t & 63;
    int wr = w >> 1, wc = w & 1;
    int row16 = lane & 15, kg = lane >> 4;
    int rA = t >> 1, hh = t & 1;
    f32x4 acc[4][2];
    #pragma unroll
    for (int mi = 0; mi < 4; ++mi)
        #pragma unroll
        for (int ni = 0; ni < 2; ++ni) acc[mi][ni] = (f32x4)(0.f);

    for (int kb = 0; kb < 768; kb += 32) {
        int tap = kb >> 8;
        int fb = kb & 255;
        {
            int nl = nloc0 + rA + tap - 1;
            uint4 v0 = make_uint4(0, 0, 0, 0), v1 = make_uint4(0, 0, 0, 0);
            if ((unsigned)nl < 4096u) {
                const uint4* src = (const uint4*)(xbf + ((size_t)(bb << 12) + nl) * 256 + fb + hh * 16);
                v0 = src[0]; v1 = src[1];
            }
            *(uint4*)&As[rA * LDW + hh * 32] = v0;
            *(uint4*)&As[rA * LDW + hh * 32 + 16] = v1;
        }
        if (t < 128) {
            int rB = t >> 1;
            const uint4* src = (const uint4*)(wcB + (size_t)(n0 + rB) * 768 + kb + hh * 16);
            uint4 v0 = src[0], v1 = src[1];
            *(uint4*)&Bs[rB * LDW + hh * 32] = v0;
            *(uint4*)&Bs[rB * LDW + hh * 32 + 16] = v1;
        }
        __syncthreads();
        bf16x8 bfr[2];
        #pragma unroll
        for (int ni = 0; ni < 2; ++ni)
            bfr[ni] = *(bf16x8*)&Bs[(wc * 32 + ni * 16 + row16) * LDW + kg * 16];
        #pragma unroll
        for (int mi = 0; mi < 4; ++mi) {
            bf16x8 afr = *(bf16x8*)&As[(wr * 64 + mi * 16 + row16) * LDW + kg * 16];
            acc[mi][0] = __builtin_amdgcn_mfma_f32_16x16x32_bf16(afr, bfr[0], acc[mi][0], 0, 0, 0);
            acc[mi][1] = __builtin_amdgcn_mfma_f32_16x16x32_bf16(afr, bfr[1], acc[mi][1], 0, 0, 0);
        }
        __syncthreads();
    }
    #pragma unroll
    for (int mi = 0; mi < 4; ++mi)
        #pragma unroll
        for (int ni = 0; ni < 2; ++ni) {
            int rowl = wr * 64 + mi * 16 + kg * 4;
            int coll = wc * 32 + ni * 16 + row16;
            int n = n0 + coll;
            float bc = tcb[n];
            #pragma unroll
            for (int q = 0; q < 4; ++q) {
                size_t node = (size_t)(m0 + rowl + q);
                float v = acc[mi][ni][q] + bc + x[node * 256 + n];
                v = v > 0.f ? v : 0.f;
                hAb[node * 256 + n] = f2b(v);
            }
        }
}

// ---------------- MFMA GEMM + fused s/d partials + last-block strip sum ----------------
__global__ __launch_bounds__(256) void k_gemm_layer(const unsigned short* __restrict__ hAb,
                                                    const unsigned short* __restrict__ WT,
                                                    const float* __restrict__ as, const float* __restrict__ ad,
                                                    unsigned short* __restrict__ hwB,
                                                    float* __restrict__ sPart, float* __restrict__ dPart,
                                                    float* __restrict__ sV, float* __restrict__ dV,
                                                    int* __restrict__ ctr) {
    __shared__ char lds[128 * LDW + 64 * LDW];
    __shared__ float sRed[256], dRed[256];
    __shared__ int lastFlag;
    char* As = lds;
    char* Bs = lds + 128 * LDW;
    int t = threadIdx.x;
    int m0 = blockIdx.x * 128, n0 = blockIdx.y * 64;
    int w = t >> 6, lane = t & 63;
    int wr = w >> 1, wc = w & 1;
    int row16 = lane & 15, kg = lane >> 4;
    int rA = t >> 1, hh = t & 1;
    f32x4 acc[4][2];
    #pragma unroll
    for (int mi = 0; mi < 4; ++mi)
        #pragma unroll
        for (int ni = 0; ni < 2; ++ni) acc[mi][ni] = (f32x4)(0.f);

    for (int kb = 0; kb < 256; kb += 32) {
        {
            const uint4* src = (const uint4*)(hAb + (size_t)(m0 + rA) * 256 + kb + hh * 16);
            uint4 v0 = src[0], v1 = src[1];
            *(uint4*)&As[rA * LDW + hh * 32] = v0;
            *(uint4*)&As[rA * LDW + hh * 32 + 16] = v1;
        }
        if (t < 128) {
            int rB = t >> 1;
            const uint4* src = (const uint4*)(WT + (size_t)(n0 + rB) * 256 + kb + hh * 16);
            uint4 v0 = src[0], v1 = src[1];
            *(uint4*)&Bs[rB * LDW + hh * 32] = v0;
            *(uint4*)&Bs[rB * LDW + hh * 32 + 16] = v1;
        }
        __syncthreads();
        bf16x8 bfr[2];
        #pragma unroll
        for (int ni = 0; ni < 2; ++ni)
            bfr[ni] = *(bf16x8*)&Bs[(wc * 32 + ni * 16 + row16) * LDW + kg * 16];
        #pragma unroll
        for (int mi = 0; mi < 4; ++mi) {
            bf16x8 afr = *(bf16x8*)&As[(wr * 64 + mi * 16 + row16) * LDW + kg * 16];
            acc[mi][0] = __builtin_amdgcn_mfma_f32_16x16x32_bf16(afr, bfr[0], acc[mi][0], 0, 0, 0);
            acc[mi][1] = __builtin_amdgcn_mfma_f32_16x16x32_bf16(afr, bfr[1], acc[mi][1], 0, 0, 0);
        }
        __syncthreads();
    }
    // hw store
    #pragma unroll
    for (int mi = 0; mi < 4; ++mi)
        #pragma unroll
        for (int ni = 0; ni < 2; ++ni) {
            int rowl = wr * 64 + mi * 16 + kg * 4;
            int coll = wc * 32 + ni * 16 + row16;
            size_t base = (size_t)(m0 + rowl) * 256 + n0 + coll;
            #pragma unroll
            for (int q = 0; q < 4; ++q) hwB[base + (size_t)q * 256] = f2b(acc[mi][ni][q]);
        }
    // fused s/d partials over this block's 64 cols
    float asv0 = as[n0 + wc * 32 + row16];
    float asv1 = as[n0 + wc * 32 + 16 + row16];
    float adv0 = ad[n0 + wc * 32 + row16];
    float adv1 = ad[n0 + wc * 32 + 16 + row16];
    #pragma unroll
    for (int mi = 0; mi < 4; ++mi)
        #pragma unroll
        for (int q = 0; q < 4; ++q) {
            float ps = acc[mi][0][q] * asv0 + acc[mi][1][q] * asv1;
            float pd = acc[mi][0][q] * adv0 + acc[mi][1][q] * adv1;
            #pragma unroll
            for (int o = 1; o < 16; o <<= 1) { ps += __shfl_xor(ps, o); pd += __shfl_xor(pd, o); }
            if (row16 == 0) {
                int rowl = wr * 64 + mi * 16 + kg * 4 + q;
                sRed[rowl * 2 + wc] = ps;
                dRed[rowl * 2 + wc] = pd;
            }
        }
    __syncthreads();
    if (t < 128) {
        sPart[(size_t)blockIdx.y * NTOT + m0 + t] = sRed[t * 2] + sRed[t * 2 + 1];
        dPart[(size_t)blockIdx.y * NTOT + m0 + t] = dRed[t * 2] + dRed[t * 2 + 1];
    }
    // last block of this 128-row strip sums the 4 partials into sV/dV
    __threadfence();
    if (t == 0) {
        int old = atomicAdd(&ctr[blockIdx.x], 1);
        lastFlag = (old == 3);
    }
    __syncthreads();
    if (lastFlag) {
        __threadfence();  // make other blocks' partial stores visible
        if (t < 128) {
            int r = m0 + t;
            sV[r] = sPart[r] + sPart[NTOT + r] + sPart[2 * NTOT + r] + sPart[3 * NTOT + r];
        } else {
            int r = m0 + t - 128;
            dV[r] = dPart[r] + dPart[NTOT + r] + dPart[2 * NTOT + r] + dPart[3 * NTOT + r];
        }
        if (t == 0) ctr[blockIdx.x] = 0;  // self-reset for next layer
    }
}

// edge softmax + aggregate: lane-parallel scoring (no max pass; scores bounded), pipelined gather
__global__ __launch_bounds__(256) void k_agg(const unsigned short* __restrict__ hwB,
                                             const float* __restrict__ sV, const float* __restrict__ dV,
                                             const int* __restrict__ off, const int* __restrict__ csr,
                                             const float* __restrict__ bias,
                                             unsigned short* __restrict__ hout) {
    int tid = threadIdx.x;
    int wave = tid >> 6, lane = tid & 63;
    int node = blockIdx.x * 4 + wave;
    int beg = off[node], end = off[node + 1];
    float di = dV[node];
    const ushort4* hw4 = (const ushort4*)hwB;
    float denom = 0.f;
    float a0 = 0.f, a1 = 0.f, a2 = 0.f, a3 = 0.f;

    for (int cbeg = beg; cbeg < end; cbeg += 64) {
        int j = cbeg + lane;
        int sj = 0;
        float myw = 0.f;
        if (j < end) {
            sj = csr[j];
            float e = sV[sj] + di;
            e = e > 0.f ? e : SLOPE * e;
            myw = __expf(e);
        }
        float csum = myw;
        #pragma unroll
        for (int o = 1; o < 64; o <<= 1) csum += __shfl_xor(csum, o);
        denom += csum;
        int cnt = end - cbeg; if (cnt > 64) cnt = 64;
        int q = 0;
        for (; q + 4 <= cnt; q += 4) {
            int s0 = __builtin_amdgcn_readlane(sj, q);
            int s1 = __builtin_amdgcn_readlane(sj, q + 1);
            int s2 = __builtin_amdgcn_readlane(sj, q + 2);
            int s3 = __builtin_amdgcn_readlane(sj, q + 3);
            float w0 = rlanef(myw, q);
            float w1 = rlanef(myw, q + 1);
            float w2 = rlanef(myw, q + 2);
            float w3 = rlanef(myw, q + 3);
            ushort4 v0 = hw4[(size_t)s0 * 64 + lane];
            ushort4 v1 = hw4[(size_t)s1 * 64 + lane];
            ushort4 v2 = hw4[(size_t)s2 * 64 + lane];
            ushort4 v3 = hw4[(size_t)s3 * 64 + lane];
            a0 = fmaf(w0, b2f(v0.x), a0); a1 = fmaf(w0, b2f(v0.y), a1);
            a2 = fmaf(w0, b2f(v0.z), a2); a3 = fmaf(w0, b2f(v0.w), a3);
            a0 = fmaf(w1, b2f(v1.x), a0); a1 = fmaf(w1, b2f(v1.y), a1);
            a2 = fmaf(w1, b2f(v1.z), a2); a3 = fmaf(w1, b2f(v1.w), a3);
            a0 = fmaf(w2, b2f(v2.x), a0); a1 = fmaf(w2, b2f(v2.y), a1);
            a2 = fmaf(w2, b2f(v2.z), a2); a3 = fmaf(w2, b2f(v2.w), a3);
            a0 = fmaf(w3, b2f(v3.x), a0); a1 = fmaf(w3, b2f(v3.y), a1);
            a2 = fmaf(w3, b2f(v3.z), a2); a3 = fmaf(w3, b2f(v3.w), a3);
        }
        for (; q < cnt; ++q) {
            int sq = __builtin_amdgcn_readlane(sj, q);
            float wq = rlanef(myw, q);
            ushort4 v = hw4[(size_t)sq * 64 + lane];
            a0 = fmaf(wq, b2f(v.x), a0); a1 = fmaf(wq, b2f(v.y), a1);
            a2 = fmaf(wq, b2f(v.z), a2); a3 = fmaf(wq, b2f(v.w), a3);
        }
    }
    float inv = 1.f / denom;
    float4 bb = ((const float4*)bias)[lane];
    ushort4 o;
    float o0 = a0 * inv + bb.x; o.x = f2b(o0 > 0.f ? o0 : 0.f);
    float o1 = a1 * inv + bb.y; o.y = f2b(o1 > 0.f ? o1 : 0.f);
    float o2 = a2 * inv + bb.z; o.z = f2b(o2 > 0.f ? o2 : 0.f);
    float o3 = a3 * inv + bb.w; o.w = f2b(o3 > 0.f ? o3 : 0.f);
    ((ushort4*)hout)[(size_t)node * 64 + lane] = o;
}

// final conv at n==0 (taps 1,2 on nodes 0,1) + LayerNorm + relu
__global__ __launch_bounds__(256) void k_final(const unsigned short* __restrict__ hAb,
                                               const float* __restrict__ wT,
                                               const float* __restrict__ tcb, const float* __restrict__ g,
                                               const float* __restrict__ bln, float* __restrict__ out) {
    __shared__ float r0[HDIM], r1[HDIM];
    __shared__ float red[16];
    int b = blockIdx.x, c = threadIdx.x;
    r0[c] = b2f(hAb[(size_t)(b * NSEQ + 0) * HDIM + c]);
    r1[c] = b2f(hAb[(size_t)(b * NSEQ + 1) * HDIM + c]);
    __syncthreads();
    float a = tcb[c];
    for (int f = 0; f < FDIM; ++f) {
        a = fmaf(wT[(1 * FDIM + f) * HDIM + c], r0[f], a);
        a = fmaf(wT[(2 * FDIM + f) * HDIM + c], r1[f], a);
    }
    float ss = a, sq = a * a;
    #pragma unroll
    for (int o = 1; o < 64; o <<= 1) { ss += __shfl_xor(ss, o); sq += __shfl_xor(sq, o); }
    int wave = c >> 6, lane = c & 63;
    if (lane == 0) { red[wave] = ss; red[8 + wave] = sq; }
    __syncthreads();
    float tot = 0.f, totq = 0.f;
    #pragma unroll
    for (int w = 0; w < 4; ++w) { tot += red[w]; totq += red[8 + w]; }
    float mu = tot * (1.f / HDIM);
    float var = totq * (1.f / HDIM) - mu * mu;
    float v = (a - mu) * rsqrtf(var + LN_EPS) * g[c] + bln[c];
    out[b * HDIM + c] = v > 0.f ? v : 0.f;
}

extern "C" void kernel_launch(void* const* d_in, const int* in_sizes, int n_in,
                              void* d_out, int out_size, void* d_ws, size_t ws_size,
                              hipStream_t stream) {
    const float* x     = (const float*)d_in[0];
    const int*   ei    = (const int*)d_in[1];
    const float* tcw   = (const float*)d_in[2];
    const float* tcb   = (const float*)d_in[3];
    const float* gatW  = (const float*)d_in[4];
    const float* gatas = (const float*)d_in[5];
    const float* gatad = (const float*)d_in[6];
    const float* gatb  = (const float*)d_in[7];
    const float* lng   = (const float*)d_in[8];
    const float* lnb   = (const float*)d_in[9];
    float* out = (float*)d_out;

    char* ws = (char*)d_ws;
    unsigned short* hAb = (unsigned short*)(ws + OFF_HA);
    unsigned short* hwB = (unsigned short*)(ws + OFF_HW);
    unsigned short* xbf = (unsigned short*)(ws + OFF_XB);
    unsigned short* wcB = (unsigned short*)(ws + OFF_WC);
    unsigned short* WTb = (unsigned short*)(ws + OFF_WL);
    float* sPart = (float*)(ws + OFF_SP);
    float* dPart = (float*)(ws + OFF_DP);
    int*   cnt  = (int*)(ws + OFF_CNT);
    int*   offA = (int*)(ws + OFF_OFF);
    int*   cur  = (int*)(ws + OFF_CUR);
    int*   csr  = (int*)(ws + OFF_CSR);
    float* wT   = (float*)(ws + OFF_WT);
    float* sV   = (float*)(ws + OFF_SV);
    float* dV   = (float*)(ws + OFF_DV);
    int*   ctr  = (int*)(ws + OFF_CTR);

    k_pre<<<5888, 256, 0, stream>>>(x, xbf, cnt, ctr, tcw, gatW, wcB, WTb, wT);
    k_count<<<NEE / 256, 256, 0, stream>>>(ei, cnt);
    k_scan<<<1, 1024, 0, stream>>>(cnt, offA, cur);
    k_scat_conv<<<1600, 256, 0, stream>>>(ei, cur, csr, xbf, x, wcB, tcb, hAb);

    for (int l = 0; l < NLAYER; ++l) {
        k_gemm_layer<<<dim3(NTOT / 128, 4), 256, 0, stream>>>(
            hAb, WTb + (size_t)l * 65536, gatas + l * HDIM, gatad + l * HDIM,
            hwB, sPart, dPart, sV, dV, ctr);
        k_agg<<<NTOT / 4, 256, 0, stream>>>(hwB, sV, dV, offA, csr, gatb + l * HDIM, hAb);
    }

    k_final<<<BBATCH, 256, 0, stream>>>(hAb, wT, tcb, lng, lnb, out);
}

// Round 7
// 194.292 us; speedup vs baseline: 1.5755x; 1.5755x over previous
//
#include <hip/hip_runtime.h>
#include <hip/hip_bf16.h>
#include <math.h>

#define NTOT 16384
#define HDIM 256
#define BBATCH 4
#define NSEQ 4096
#define FDIM 256
#define NE 262144
#define NEE (NE + NTOT)
#define NLAYER 3
#define LN_EPS 1e-5f
#define SLOPE 0.2f

typedef __attribute__((ext_vector_type(8))) short bf16x8;
typedef __attribute__((ext_vector_type(4))) float f32x4;

#define LDW 80   // LDS row stride in bytes (64B payload + 16B pad -> 2-way bank alias, free)

// ---- workspace layout (bytes) ----
#define OFF_HA   0u          // ushort[NTOT*256]  8388608   node features (bf16)
#define OFF_HW   8388608u    // ushort[NTOT*256]  8388608   hw = h@W (bf16)
#define OFF_XB   16777216u   // ushort[NTOT*256]  8388608   x in bf16
#define OFF_WC   25165824u   // ushort[256*768]   393216    conv weight^T bf16, k = tap*256+f
#define OFF_WL   25559040u   // ushort[3*256*256] 393216    layer W^T bf16
#define OFF_SP   25952256u   // float[4*NTOT]     262144    s partials (per col-block)
#define OFF_DP   26214400u   // float[4*NTOT]     262144    d partials
#define OFF_CNT  26476544u   // int[NTOT]
#define OFF_OFF  26542080u   // int[NTOT+1] (pad 65792)
#define OFF_CUR  26607872u   // int[NTOT]
#define OFF_CSR  26673408u   // int[NEE] 1114112
#define OFF_WT   27787520u   // float[3*256*256]  786432   fp32 conv weight^T for k_final
#define OFF_SV   28573952u   // float[NTOT]       65536    s summed
#define OFF_DV   28639488u   // float[NTOT]       65536    d summed
// total ~28.7 MB

static __device__ __forceinline__ unsigned short f2b(float f) {
    __hip_bfloat16 h = __float2bfloat16(f);
    return __builtin_bit_cast(unsigned short, h);
}
static __device__ __forceinline__ float b2f(unsigned short u) {
    __hip_bfloat16 h = __builtin_bit_cast(__hip_bfloat16, u);
    return __bfloat162float(h);
}
static __device__ __forceinline__ float rlanef(float v, int l) {
    return __builtin_bit_cast(float, __builtin_amdgcn_readlane(__builtin_bit_cast(int, v), l));
}

// ---- merged pre-pass: x->bf16 (+zero cnt), weight prep ----
// grid: [0,4096) xbf ; [4096,5888) prep.  (count is a SEPARATE kernel: stream
// ordering guarantees cnt is zeroed before any atomicAdd.)
__global__ __launch_bounds__(256) void k_pre(const float* __restrict__ x, unsigned short* __restrict__ xb,
                                             int* __restrict__ cnt,
                                             const float* __restrict__ tcw, const float* __restrict__ gatW,
                                             unsigned short* __restrict__ wcB, unsigned short* __restrict__ WTb,
                                             float* __restrict__ wT) {
    int b = blockIdx.x, t = threadIdx.x;
    if (b < 4096) {
        int i = (b * 256 + t) * 4;
        float4 v = *(const float4*)(x + i);
        ushort4 o;
        o.x = f2b(v.x); o.y = f2b(v.y); o.z = f2b(v.z); o.w = f2b(v.w);
        *(ushort4*)(xb + i) = o;
        if (b < 16) *(int4*)(cnt + i) = make_int4(0, 0, 0, 0);   // 16*256*4 = 16384 ints
    } else {
        int bb = b - 4096;
        if (bb < 256) {
            const float* s = tcw + bb * 768 + t * 3;
            wcB[bb * 768 + 0 + t]   = f2b(s[0]);
            wcB[bb * 768 + 256 + t] = f2b(s[1]);
            wcB[bb * 768 + 512 + t] = f2b(s[2]);
        } else if (bb < 1024) {
            int ln = bb - 256; int n = ln & 255; int l = ln >> 8;
            WTb[(size_t)l * 65536 + n * 256 + t] = f2b(gatW[(size_t)l * 65536 + t * 256 + n]);
        } else {
            int fk = bb - 1024; int f = fk / 3, k = fk - 3 * f;
            wT[(k * FDIM + f) * HDIM + t] = tcw[t * 768 + fk];
        }
    }
}

__global__ __launch_bounds__(256) void k_count(const int* __restrict__ ei, int* __restrict__ cnt) {
    int e = blockIdx.x * 256 + threadIdx.x;
    int dst = (e < NE) ? ei[NE + e] : (e - NE);
    atomicAdd(&cnt[dst], 1);
}

__global__ __launch_bounds__(1024) void k_scan(const int* __restrict__ cnt, int* __restrict__ off,
                                               int* __restrict__ cur) {
    __shared__ int sums[1024];
    int t = threadIdx.x;
    int base = t * 16;
    int c[16]; int s = 0;
    #pragma unroll
    for (int j = 0; j < 16; ++j) { c[j] = cnt[base + j]; s += c[j]; }
    sums[t] = s;
    __syncthreads();
    for (int dstep = 1; dstep < 1024; dstep <<= 1) {
        int v = (t >= dstep) ? sums[t - dstep] : 0;
        __syncthreads();
        sums[t] += v;
        __syncthreads();
    }
    int pre = (t == 0) ? 0 : sums[t - 1];
    #pragma unroll
    for (int j = 0; j < 16; ++j) { off[base + j] = pre; cur[base + j] = pre; pre += c[j]; }
    if (t == 1023) off[NTOT] = pre;
}

// ---- merged: CSR scatter [0,1088) + conv GEMM [1088,1600) ----
__global__ __launch_bounds__(256) void k_scat_conv(const int* __restrict__ ei, int* __restrict__ cur,
                                                   int* __restrict__ csr,
                                                   const unsigned short* __restrict__ xbf,
                                                   const float* __restrict__ x,
                                                   const unsigned short* __restrict__ wcB,
                                                   const float* __restrict__ tcb,
                                                   unsigned short* __restrict__ hAb) {
    __shared__ char lds[128 * LDW + 64 * LDW];
    int t = threadIdx.x;
    if (blockIdx.x < 1088) {
        int e = blockIdx.x * 256 + t;
        int src, dst;
        if (e < NE) { src = ei[e]; dst = ei[NE + e]; } else { src = dst = e - NE; }
        int pos = atomicAdd(&cur[dst], 1);
        csr[pos] = src;
        return;
    }
    int blk = blockIdx.x - 1088;
    char* As = lds;
    char* Bs = lds + 128 * LDW;
    int m0 = (blk & 127) * 128, n0 = (blk >> 7) * 64;
    int bb = m0 >> 12;
    int nloc0 = m0 & 4095;
    int w = t >> 6, lane = t & 63;
    int wr = w >> 1, wc = w & 1;
    int row16 = lane & 15, kg = lane >> 4;
    int rA = t >> 1, hh = t & 1;
    f32x4 acc[4][2];
    #pragma unroll
    for (int mi = 0; mi < 4; ++mi)
        #pragma unroll
        for (int ni = 0; ni < 2; ++ni) acc[mi][ni] = (f32x4)(0.f);

    for (int kb = 0; kb < 768; kb += 32) {
        int tap = kb >> 8;
        int fb = kb & 255;
        {
            int nl = nloc0 + rA + tap - 1;
            uint4 v0 = make_uint4(0, 0, 0, 0), v1 = make_uint4(0, 0, 0, 0);
            if ((unsigned)nl < 4096u) {
                const uint4* src = (const uint4*)(xbf + ((size_t)(bb << 12) + nl) * 256 + fb + hh * 16);
                v0 = src[0]; v1 = src[1];
            }
            *(uint4*)&As[rA * LDW + hh * 32] = v0;
            *(uint4*)&As[rA * LDW + hh * 32 + 16] = v1;
        }
        if (t < 128) {
            int rB = t >> 1;
            const uint4* src = (const uint4*)(wcB + (size_t)(n0 + rB) * 768 + kb + hh * 16);
            uint4 v0 = src[0], v1 = src[1];
            *(uint4*)&Bs[rB * LDW + hh * 32] = v0;
            *(uint4*)&Bs[rB * LDW + hh * 32 + 16] = v1;
        }
        __syncthreads();
        bf16x8 bfr[2];
        #pragma unroll
        for (int ni = 0; ni < 2; ++ni)
            bfr[ni] = *(bf16x8*)&Bs[(wc * 32 + ni * 16 + row16) * LDW + kg * 16];
        #pragma unroll
        for (int mi = 0; mi < 4; ++mi) {
            bf16x8 afr = *(bf16x8*)&As[(wr * 64 + mi * 16 + row16) * LDW + kg * 16];
            acc[mi][0] = __builtin_amdgcn_mfma_f32_16x16x32_bf16(afr, bfr[0], acc[mi][0], 0, 0, 0);
            acc[mi][1] = __builtin_amdgcn_mfma_f32_16x16x32_bf16(afr, bfr[1], acc[mi][1], 0, 0, 0);
        }
        __syncthreads();
    }
    #pragma unroll
    for (int mi = 0; mi < 4; ++mi)
        #pragma unroll
        for (int ni = 0; ni < 2; ++ni) {
            int rowl = wr * 64 + mi * 16 + kg * 4;
            int coll = wc * 32 + ni * 16 + row16;
            int n = n0 + coll;
            float bc = tcb[n];
            #pragma unroll
            for (int q = 0; q < 4; ++q) {
                size_t node = (size_t)(m0 + rowl + q);
                float v = acc[mi][ni][q] + bc + x[node * 256 + n];
                v = v > 0.f ? v : 0.f;
                hAb[node * 256 + n] = f2b(v);
            }
        }
}

// ---------------- MFMA GEMM + fused s/d partials (NO fence/ctr — see round-6 post-mortem:
// per-block __threadfence forced L2 writebacks, 58us/dispatch of stall) ----------------
__global__ __launch_bounds__(256) void k_gemm_layer(const unsigned short* __restrict__ hAb,
                                                    const unsigned short* __restrict__ WT,
                                                    const float* __restrict__ as, const float* __restrict__ ad,
                                                    unsigned short* __restrict__ hwB,
                                                    float* __restrict__ sPart, float* __restrict__ dPart) {
    __shared__ char lds[128 * LDW + 64 * LDW];
    __shared__ float sRed[256], dRed[256];
    char* As = lds;
    char* Bs = lds + 128 * LDW;
    int t = threadIdx.x;
    int m0 = blockIdx.x * 128, n0 = blockIdx.y * 64;
    int w = t >> 6, lane = t & 63;
    int wr = w >> 1, wc = w & 1;
    int row16 = lane & 15, kg = lane >> 4;
    int rA = t >> 1, hh = t & 1;
    f32x4 acc[4][2];
    #pragma unroll
    for (int mi = 0; mi < 4; ++mi)
        #pragma unroll
        for (int ni = 0; ni < 2; ++ni) acc[mi][ni] = (f32x4)(0.f);

    for (int kb = 0; kb < 256; kb += 32) {
        {
            const uint4* src = (const uint4*)(hAb + (size_t)(m0 + rA) * 256 + kb + hh * 16);
            uint4 v0 = src[0], v1 = src[1];
            *(uint4*)&As[rA * LDW + hh * 32] = v0;
            *(uint4*)&As[rA * LDW + hh * 32 + 16] = v1;
        }
        if (t < 128) {
            int rB = t >> 1;
            const uint4* src = (const uint4*)(WT + (size_t)(n0 + rB) * 256 + kb + hh * 16);
            uint4 v0 = src[0], v1 = src[1];
            *(uint4*)&Bs[rB * LDW + hh * 32] = v0;
            *(uint4*)&Bs[rB * LDW + hh * 32 + 16] = v1;
        }
        __syncthreads();
        bf16x8 bfr[2];
        #pragma unroll
        for (int ni = 0; ni < 2; ++ni)
            bfr[ni] = *(bf16x8*)&Bs[(wc * 32 + ni * 16 + row16) * LDW + kg * 16];
        #pragma unroll
        for (int mi = 0; mi < 4; ++mi) {
            bf16x8 afr = *(bf16x8*)&As[(wr * 64 + mi * 16 + row16) * LDW + kg * 16];
            acc[mi][0] = __builtin_amdgcn_mfma_f32_16x16x32_bf16(afr, bfr[0], acc[mi][0], 0, 0, 0);
            acc[mi][1] = __builtin_amdgcn_mfma_f32_16x16x32_bf16(afr, bfr[1], acc[mi][1], 0, 0, 0);
        }
        __syncthreads();
    }
    // hw store
    #pragma unroll
    for (int mi = 0; mi < 4; ++mi)
        #pragma unroll
        for (int ni = 0; ni < 2; ++ni) {
            int rowl = wr * 64 + mi * 16 + kg * 4;
            int coll = wc * 32 + ni * 16 + row16;
            size_t base = (size_t)(m0 + rowl) * 256 + n0 + coll;
            #pragma unroll
            for (int q = 0; q < 4; ++q) hwB[base + (size_t)q * 256] = f2b(acc[mi][ni][q]);
        }
    // fused s/d partials over this block's 64 cols
    float asv0 = as[n0 + wc * 32 + row16];
    float asv1 = as[n0 + wc * 32 + 16 + row16];
    float adv0 = ad[n0 + wc * 32 + row16];
    float adv1 = ad[n0 + wc * 32 + 16 + row16];
    #pragma unroll
    for (int mi = 0; mi < 4; ++mi)
        #pragma unroll
        for (int q = 0; q < 4; ++q) {
            float ps = acc[mi][0][q] * asv0 + acc[mi][1][q] * asv1;
            float pd = acc[mi][0][q] * adv0 + acc[mi][1][q] * adv1;
            #pragma unroll
            for (int o = 1; o < 16; o <<= 1) { ps += __shfl_xor(ps, o); pd += __shfl_xor(pd, o); }
            if (row16 == 0) {
                int rowl = wr * 64 + mi * 16 + kg * 4 + q;
                sRed[rowl * 2 + wc] = ps;
                dRed[rowl * 2 + wc] = pd;
            }
        }
    __syncthreads();
    if (t < 128) {
        sPart[(size_t)blockIdx.y * NTOT + m0 + t] = sRed[t * 2] + sRed[t * 2 + 1];
        dPart[(size_t)blockIdx.y * NTOT + m0 + t] = dRed[t * 2] + dRed[t * 2 + 1];
    }
}

// tiny cross-block reduction: sV/dV = sum of 4 col-block partials
__global__ __launch_bounds__(256) void k_sdsum(const float* __restrict__ sPart, const float* __restrict__ dPart,
                                               float* __restrict__ sV, float* __restrict__ dV) {
    int r = blockIdx.x * 256 + threadIdx.x;
    sV[r] = sPart[r] + sPart[NTOT + r] + sPart[2 * NTOT + r] + sPart[3 * NTOT + r];
    dV[r] = dPart[r] + dPart[NTOT + r] + dPart[2 * NTOT + r] + dPart[3 * NTOT + r];
}

// edge softmax + aggregate: lane-parallel scoring (no max pass; scores bounded), pipelined gather
__global__ __launch_bounds__(256) void k_agg(const unsigned short* __restrict__ hwB,
                                             const float* __restrict__ sV, const float* __restrict__ dV,
                                             const int* __restrict__ off, const int* __restrict__ csr,
                                             const float* __restrict__ bias,
                                             unsigned short* __restrict__ hout) {
    int tid = threadIdx.x;
    int wave = tid >> 6, lane = tid & 63;
    int node = blockIdx.x * 4 + wave;
    int beg = off[node], end = off[node + 1];
    float di = dV[node];
    const ushort4* hw4 = (const ushort4*)hwB;
    float denom = 0.f;
    float a0 = 0.f, a1 = 0.f, a2 = 0.f, a3 = 0.f;

    for (int cbeg = beg; cbeg < end; cbeg += 64) {
        int j = cbeg + lane;
        int sj = 0;
        float myw = 0.f;
        if (j < end) {
            sj = csr[j];
            float e = sV[sj] + di;
            e = e > 0.f ? e : SLOPE * e;
            myw = __expf(e);
        }
        float csum = myw;
        #pragma unroll
        for (int o = 1; o < 64; o <<= 1) csum += __shfl_xor(csum, o);
        denom += csum;
        int cnt = end - cbeg; if (cnt > 64) cnt = 64;
        int q = 0;
        for (; q + 4 <= cnt; q += 4) {
            int s0 = __builtin_amdgcn_readlane(sj, q);
            int s1 = __builtin_amdgcn_readlane(sj, q + 1);
            int s2 = __builtin_amdgcn_readlane(sj, q + 2);
            int s3 = __builtin_amdgcn_readlane(sj, q + 3);
            float w0 = rlanef(myw, q);
            float w1 = rlanef(myw, q + 1);
            float w2 = rlanef(myw, q + 2);
            float w3 = rlanef(myw, q + 3);
            ushort4 v0 = hw4[(size_t)s0 * 64 + lane];
            ushort4 v1 = hw4[(size_t)s1 * 64 + lane];
            ushort4 v2 = hw4[(size_t)s2 * 64 + lane];
            ushort4 v3 = hw4[(size_t)s3 * 64 + lane];
            a0 = fmaf(w0, b2f(v0.x), a0); a1 = fmaf(w0, b2f(v0.y), a1);
            a2 = fmaf(w0, b2f(v0.z), a2); a3 = fmaf(w0, b2f(v0.w), a3);
            a0 = fmaf(w1, b2f(v1.x), a0); a1 = fmaf(w1, b2f(v1.y), a1);
            a2 = fmaf(w1, b2f(v1.z), a2); a3 = fmaf(w1, b2f(v1.w), a3);
            a0 = fmaf(w2, b2f(v2.x), a0); a1 = fmaf(w2, b2f(v2.y), a1);
            a2 = fmaf(w2, b2f(v2.z), a2); a3 = fmaf(w2, b2f(v2.w), a3);
            a0 = fmaf(w3, b2f(v3.x), a0); a1 = fmaf(w3, b2f(v3.y), a1);
            a2 = fmaf(w3, b2f(v3.z), a2); a3 = fmaf(w3, b2f(v3.w), a3);
        }
        for (; q < cnt; ++q) {
            int sq = __builtin_amdgcn_readlane(sj, q);
            float wq = rlanef(myw, q);
            ushort4 v = hw4[(size_t)sq * 64 + lane];
            a0 = fmaf(wq, b2f(v.x), a0); a1 = fmaf(wq, b2f(v.y), a1);
            a2 = fmaf(wq, b2f(v.z), a2); a3 = fmaf(wq, b2f(v.w), a3);
        }
    }
    float inv = 1.f / denom;
    float4 bb = ((const float4*)bias)[lane];
    ushort4 o;
    float o0 = a0 * inv + bb.x; o.x = f2b(o0 > 0.f ? o0 : 0.f);
    float o1 = a1 * inv + bb.y; o.y = f2b(o1 > 0.f ? o1 : 0.f);
    float o2 = a2 * inv + bb.z; o.z = f2b(o2 > 0.f ? o2 : 0.f);
    float o3 = a3 * inv + bb.w; o.w = f2b(o3 > 0.f ? o3 : 0.f);
    ((ushort4*)hout)[(size_t)node * 64 + lane] = o;
}

// final conv at n==0 (taps 1,2 on nodes 0,1) + LayerNorm + relu
__global__ __launch_bounds__(256) void k_final(const unsigned short* __restrict__ hAb,
                                               const float* __restrict__ wT,
                                               const float* __restrict__ tcb, const float* __restrict__ g,
                                               const float* __restrict__ bln, float* __restrict__ out) {
    __shared__ float r0[HDIM], r1[HDIM];
    __shared__ float red[16];
    int b = blockIdx.x, c = threadIdx.x;
    r0[c] = b2f(hAb[(size_t)(b * NSEQ + 0) * HDIM + c]);
    r1[c] = b2f(hAb[(size_t)(b * NSEQ + 1) * HDIM + c]);
    __syncthreads();
    float a = tcb[c];
    for (int f = 0; f < FDIM; ++f) {
        a = fmaf(wT[(1 * FDIM + f) * HDIM + c], r0[f], a);
        a = fmaf(wT[(2 * FDIM + f) * HDIM + c], r1[f], a);
    }
    float ss = a, sq = a * a;
    #pragma unroll
    for (int o = 1; o < 64; o <<= 1) { ss += __shfl_xor(ss, o); sq += __shfl_xor(sq, o); }
    int wave = c >> 6, lane = c & 63;
    if (lane == 0) { red[wave] = ss; red[8 + wave] = sq; }
    __syncthreads();
    float tot = 0.f, totq = 0.f;
    #pragma unroll
    for (int w = 0; w < 4; ++w) { tot += red[w]; totq += red[8 + w]; }
    float mu = tot * (1.f / HDIM);
    float var = totq * (1.f / HDIM) - mu * mu;
    float v = (a - mu) * rsqrtf(var + LN_EPS) * g[c] + bln[c];
    out[b * HDIM + c] = v > 0.f ? v : 0.f;
}

extern "C" void kernel_launch(void* const* d_in, const int* in_sizes, int n_in,
                              void* d_out, int out_size, void* d_ws, size_t ws_size,
                              hipStream_t stream) {
    const float* x     = (const float*)d_in[0];
    const int*   ei    = (const int*)d_in[1];
    const float* tcw   = (const float*)d_in[2];
    const float* tcb   = (const float*)d_in[3];
    const float* gatW  = (const float*)d_in[4];
    const float* gatas = (const float*)d_in[5];
    const float* gatad = (const float*)d_in[6];
    const float* gatb  = (const float*)d_in[7];
    const float* lng   = (const float*)d_in[8];
    const float* lnb   = (const float*)d_in[9];
    float* out = (float*)d_out;

    char* ws = (char*)d_ws;
    unsigned short* hAb = (unsigned short*)(ws + OFF_HA);
    unsigned short* hwB = (unsigned short*)(ws + OFF_HW);
    unsigned short* xbf = (unsigned short*)(ws + OFF_XB);
    unsigned short* wcB = (unsigned short*)(ws + OFF_WC);
    unsigned short* WTb = (unsigned short*)(ws + OFF_WL);
    float* sPart = (float*)(ws + OFF_SP);
    float* dPart = (float*)(ws + OFF_DP);
    int*   cnt  = (int*)(ws + OFF_CNT);
    int*   offA = (int*)(ws + OFF_OFF);
    int*   cur  = (int*)(ws + OFF_CUR);
    int*   csr  = (int*)(ws + OFF_CSR);
    float* wT   = (float*)(ws + OFF_WT);
    float* sV   = (float*)(ws + OFF_SV);
    float* dV   = (float*)(ws + OFF_DV);

    k_pre<<<5888, 256, 0, stream>>>(x, xbf, cnt, tcw, gatW, wcB, WTb, wT);
    k_count<<<NEE / 256, 256, 0, stream>>>(ei, cnt);
    k_scan<<<1, 1024, 0, stream>>>(cnt, offA, cur);
    k_scat_conv<<<1600, 256, 0, stream>>>(ei, cur, csr, xbf, x, wcB, tcb, hAb);

    for (int l = 0; l < NLAYER; ++l) {
        k_gemm_layer<<<dim3(NTOT / 128, 4), 256, 0, stream>>>(
            hAb, WTb + (size_t)l * 65536, gatas + l * HDIM, gatad + l * HDIM, hwB, sPart, dPart);
        k_sdsum<<<NTOT / 256, 256, 0, stream>>>(sPart, dPart, sV, dV);
        k_agg<<<NTOT / 4, 256, 0, stream>>>(hwB, sV, dV, offA, csr, gatb + l * HDIM, hAb);
    }

    k_final<<<BBATCH, 256, 0, stream>>>(hAb, wT, tcb, lng, lnb, out);
}

// Round 8
// 186.025 us; speedup vs baseline: 1.6455x; 1.0444x over previous
//
#include <hip/hip_runtime.h>
#include <hip/hip_bf16.h>
#include <math.h>

#define NTOT 16384
#define HDIM 256
#define BBATCH 4
#define NSEQ 4096
#define FDIM 256
#define NE 262144
#define NEE (NE + NTOT)
#define NLAYER 3
#define LN_EPS 1e-5f
#define SLOPE 0.2f

typedef __attribute__((ext_vector_type(8))) short bf16x8;
typedef __attribute__((ext_vector_type(4))) float f32x4;

#define LDW 80    // B/LDS row stride bytes (64B payload + 16B pad)
#define SLDW 72   // conv slab row stride bytes (64B payload + 8B pad -> 18-word stride, conflict-free b128)

// ---- workspace layout (bytes) ----
#define OFF_HA   0u          // ushort[NTOT*256]  8388608   node features (bf16)
#define OFF_HW   8388608u    // ushort[NTOT*256]  8388608   hw = h@W (bf16)
#define OFF_XB   16777216u   // ushort[NTOT*256]  8388608   x in bf16
#define OFF_WC   25165824u   // ushort[256*768]   393216    conv weight^T bf16, k = tap*256+f
#define OFF_WL   25559040u   // ushort[3*256*256] 393216    layer W^T bf16
#define OFF_SP   25952256u   // float[4*NTOT]     262144    s partials (per col-block)
#define OFF_DP   26214400u   // float[4*NTOT]     262144    d partials
#define OFF_CNT  26476544u   // int[NTOT]
#define OFF_OFF  26542080u   // int[NTOT+1] (pad 65792)
#define OFF_CUR  26607872u   // int[NTOT]
#define OFF_CSR  26673408u   // int[NEE] 1114112
#define OFF_WT   27787520u   // float[3*256*256]  786432   fp32 conv weight^T for k_final
#define OFF_SV   28573952u   // float[NTOT]       65536    s summed
#define OFF_DV   28639488u   // float[NTOT]       65536    d summed
// total ~28.7 MB

static __device__ __forceinline__ unsigned short f2b(float f) {
    __hip_bfloat16 h = __float2bfloat16(f);
    return __builtin_bit_cast(unsigned short, h);
}
static __device__ __forceinline__ float b2f(unsigned short u) {
    __hip_bfloat16 h = __builtin_bit_cast(__hip_bfloat16, u);
    return __bfloat162float(h);
}
static __device__ __forceinline__ float rlanef(float v, int l) {
    return __builtin_bit_cast(float, __builtin_amdgcn_readlane(__builtin_bit_cast(int, v), l));
}

// ---- merged pre-pass: x->bf16 (+zero cnt), weight prep ----
__global__ __launch_bounds__(256) void k_pre(const float* __restrict__ x, unsigned short* __restrict__ xb,
                                             int* __restrict__ cnt,
                                             const float* __restrict__ tcw, const float* __restrict__ gatW,
                                             unsigned short* __restrict__ wcB, unsigned short* __restrict__ WTb,
                                             float* __restrict__ wT) {
    int b = blockIdx.x, t = threadIdx.x;
    if (b < 4096) {
        int i = (b * 256 + t) * 4;
        float4 v = *(const float4*)(x + i);
        ushort4 o;
        o.x = f2b(v.x); o.y = f2b(v.y); o.z = f2b(v.z); o.w = f2b(v.w);
        *(ushort4*)(xb + i) = o;
        if (b < 16) *(int4*)(cnt + i) = make_int4(0, 0, 0, 0);
    } else {
        int bb = b - 4096;
        if (bb < 256) {
            const float* s = tcw + bb * 768 + t * 3;
            wcB[bb * 768 + 0 + t]   = f2b(s[0]);
            wcB[bb * 768 + 256 + t] = f2b(s[1]);
            wcB[bb * 768 + 512 + t] = f2b(s[2]);
        } else if (bb < 1024) {
            int ln = bb - 256; int n = ln & 255; int l = ln >> 8;
            WTb[(size_t)l * 65536 + n * 256 + t] = f2b(gatW[(size_t)l * 65536 + t * 256 + n]);
        } else {
            int fk = bb - 1024; int f = fk / 3, k = fk - 3 * f;
            wT[(k * FDIM + f) * HDIM + t] = tcw[t * 768 + fk];
        }
    }
}

__global__ __launch_bounds__(256) void k_count(const int* __restrict__ ei, int* __restrict__ cnt) {
    int e = blockIdx.x * 256 + threadIdx.x;
    int dst = (e < NE) ? ei[NE + e] : (e - NE);
    atomicAdd(&cnt[dst], 1);
}

__global__ __launch_bounds__(1024) void k_scan(const int* __restrict__ cnt, int* __restrict__ off,
                                               int* __restrict__ cur) {
    __shared__ int sums[1024];
    int t = threadIdx.x;
    int base = t * 16;
    int c[16]; int s = 0;
    #pragma unroll
    for (int j = 0; j < 16; ++j) { c[j] = cnt[base + j]; s += c[j]; }
    sums[t] = s;
    __syncthreads();
    for (int dstep = 1; dstep < 1024; dstep <<= 1) {
        int v = (t >= dstep) ? sums[t - dstep] : 0;
        __syncthreads();
        sums[t] += v;
        __syncthreads();
    }
    int pre = (t == 0) ? 0 : sums[t - 1];
    #pragma unroll
    for (int j = 0; j < 16; ++j) { off[base + j] = pre; cur[base + j] = pre; pre += c[j]; }
    if (t == 1023) off[NTOT] = pre;
}

__global__ __launch_bounds__(256) void k_scatter(const int* __restrict__ ei, int* __restrict__ cur,
                                                 int* __restrict__ csr) {
    int e = blockIdx.x * 256 + threadIdx.x;
    int src, dst;
    if (e < NE) { src = ei[e]; dst = ei[NE + e]; } else { src = dst = e - NE; }
    int pos = atomicAdd(&cur[dst], 1);
    csr[pos] = src;
}

// ---------------- conv GEMM with halo slab: M=16384, N=256, K=8 steps x (3 taps x 32) ----------------
// Per K-step: stage x rows [m0-1, m0+128] x 32 cols ONCE; all 3 taps read the slab
// at row offset +tap. 16 barriers total (vs 48), 3x less A staging than tap-major im2col.
__global__ __launch_bounds__(256) void k_conv(const unsigned short* __restrict__ xbf,
                                              const float* __restrict__ x,
                                              const unsigned short* __restrict__ wcB,
                                              const float* __restrict__ tcb,
                                              unsigned short* __restrict__ hAb) {
    __shared__ char slab[130 * SLDW];      // 9360 B
    __shared__ char Bs[3 * 64 * LDW];      // 15360 B
    int t = threadIdx.x;
    int m0 = blockIdx.x * 128, n0 = blockIdx.y * 64;
    int bb = m0 >> 12;
    int nloc0 = m0 & 4095;
    int w = t >> 6, lane = t & 63;
    int wr = w >> 1, wc = w & 1;
    int row16 = lane & 15, kg = lane >> 4;
    int rA = t >> 1, hh = t & 1;
    f32x4 acc[4][2];
    #pragma unroll
    for (int mi = 0; mi < 4; ++mi)
        #pragma unroll
        for (int ni = 0; ni < 2; ++ni) acc[mi][ni] = (f32x4)(0.f);

    for (int kb = 0; kb < 8; ++kb) {
        int c0 = kb * 32;
        __syncthreads();   // previous step's MFMA reads complete before overwrite
        {   // slab rows 0..127 (2 threads/row, 32B each)
            int nl = nloc0 - 1 + rA;
            uint4 v0 = make_uint4(0, 0, 0, 0), v1 = make_uint4(0, 0, 0, 0);
            if ((unsigned)nl < 4096u) {
                const uint4* s = (const uint4*)(xbf + ((size_t)(bb << 12) + nl) * 256 + c0 + hh * 16);
                v0 = s[0]; v1 = s[1];
            }
            *(uint4*)&slab[rA * SLDW + hh * 32] = v0;
            *(uint4*)&slab[rA * SLDW + hh * 32 + 16] = v1;
        }
        if (t < 8) {  // slab rows 128,129 (4 threads/row, 16B each)
            int r = 128 + (t >> 2), u = t & 3;
            int nl = nloc0 - 1 + r;
            uint4 v = make_uint4(0, 0, 0, 0);
            if ((unsigned)nl < 4096u)
                v = *(const uint4*)(xbf + ((size_t)(bb << 12) + nl) * 256 + c0 + u * 8);
            *(uint4*)&slab[r * SLDW + u * 16] = v;
        }
        {   // B: 3 taps x 64 rows x 64B
            int rB = t >> 2, u = t & 3;
            const unsigned short* wrow = wcB + (size_t)(n0 + rB) * 768 + c0 + u * 8;
            #pragma unroll
            for (int p = 0; p < 3; ++p)
                *(uint4*)&Bs[p * 64 * LDW + rB * LDW + u * 16] = *(const uint4*)(wrow + p * 256);
        }
        __syncthreads();
        #pragma unroll
        for (int p = 0; p < 3; ++p) {
            bf16x8 bfr[2];
            #pragma unroll
            for (int ni = 0; ni < 2; ++ni)
                bfr[ni] = *(bf16x8*)&Bs[p * 64 * LDW + (wc * 32 + ni * 16 + row16) * LDW + kg * 16];
            #pragma unroll
            for (int mi = 0; mi < 4; ++mi) {
                bf16x8 afr = *(bf16x8*)&slab[(wr * 64 + mi * 16 + row16 + p) * SLDW + kg * 16];
                acc[mi][0] = __builtin_amdgcn_mfma_f32_16x16x32_bf16(afr, bfr[0], acc[mi][0], 0, 0, 0);
                acc[mi][1] = __builtin_amdgcn_mfma_f32_16x16x32_bf16(afr, bfr[1], acc[mi][1], 0, 0, 0);
            }
        }
    }
    #pragma unroll
    for (int mi = 0; mi < 4; ++mi)
        #pragma unroll
        for (int ni = 0; ni < 2; ++ni) {
            int rowl = wr * 64 + mi * 16 + kg * 4;
            int coll = wc * 32 + ni * 16 + row16;
            int n = n0 + coll;
            float bc = tcb[n];
            #pragma unroll
            for (int q = 0; q < 4; ++q) {
                size_t node = (size_t)(m0 + rowl + q);
                float v = acc[mi][ni][q] + bc + x[node * 256 + n];   // exact fp32 residual
                v = v > 0.f ? v : 0.f;
                hAb[node * 256 + n] = f2b(v);
            }
        }
}

// ---------------- MFMA GEMM + fused s/d partials (no fence — see round-6 post-mortem) ----------------
__global__ __launch_bounds__(256) void k_gemm_layer(const unsigned short* __restrict__ hAb,
                                                    const unsigned short* __restrict__ WT,
                                                    const float* __restrict__ as, const float* __restrict__ ad,
                                                    unsigned short* __restrict__ hwB,
                                                    float* __restrict__ sPart, float* __restrict__ dPart) {
    __shared__ char lds[128 * LDW + 64 * LDW];
    __shared__ float sRed[256], dRed[256];
    char* As = lds;
    char* Bs = lds + 128 * LDW;
    int t = threadIdx.x;
    int m0 = blockIdx.x * 128, n0 = blockIdx.y * 64;
    int w = t >> 6, lane = t & 63;
    int wr = w >> 1, wc = w & 1;
    int row16 = lane & 15, kg = lane >> 4;
    int rA = t >> 1, hh = t & 1;
    f32x4 acc[4][2];
    #pragma unroll
    for (int mi = 0; mi < 4; ++mi)
        #pragma unroll
        for (int ni = 0; ni < 2; ++ni) acc[mi][ni] = (f32x4)(0.f);

    for (int kb = 0; kb < 256; kb += 32) {
        {
            const uint4* src = (const uint4*)(hAb + (size_t)(m0 + rA) * 256 + kb + hh * 16);
            uint4 v0 = src[0], v1 = src[1];
            *(uint4*)&As[rA * LDW + hh * 32] = v0;
            *(uint4*)&As[rA * LDW + hh * 32 + 16] = v1;
        }
        if (t < 128) {
            int rB = t >> 1;
            const uint4* src = (const uint4*)(WT + (size_t)(n0 + rB) * 256 + kb + hh * 16);
            uint4 v0 = src[0], v1 = src[1];
            *(uint4*)&Bs[rB * LDW + hh * 32] = v0;
            *(uint4*)&Bs[rB * LDW + hh * 32 + 16] = v1;
        }
        __syncthreads();
        bf16x8 bfr[2];
        #pragma unroll
        for (int ni = 0; ni < 2; ++ni)
            bfr[ni] = *(bf16x8*)&Bs[(wc * 32 + ni * 16 + row16) * LDW + kg * 16];
        #pragma unroll
        for (int mi = 0; mi < 4; ++mi) {
            bf16x8 afr = *(bf16x8*)&As[(wr * 64 + mi * 16 + row16) * LDW + kg * 16];
            acc[mi][0] = __builtin_amdgcn_mfma_f32_16x16x32_bf16(afr, bfr[0], acc[mi][0], 0, 0, 0);
            acc[mi][1] = __builtin_amdgcn_mfma_f32_16x16x32_bf16(afr, bfr[1], acc[mi][1], 0, 0, 0);
        }
        __syncthreads();
    }
    #pragma unroll
    for (int mi = 0; mi < 4; ++mi)
        #pragma unroll
        for (int ni = 0; ni < 2; ++ni) {
            int rowl = wr * 64 + mi * 16 + kg * 4;
            int coll = wc * 32 + ni * 16 + row16;
            size_t base = (size_t)(m0 + rowl) * 256 + n0 + coll;
            #pragma unroll
            for (int q = 0; q < 4; ++q) hwB[base + (size_t)q * 256] = f2b(acc[mi][ni][q]);
        }
    float asv0 = as[n0 + wc * 32 + row16];
    float asv1 = as[n0 + wc * 32 + 16 + row16];
    float adv0 = ad[n0 + wc * 32 + row16];
    float adv1 = ad[n0 + wc * 32 + 16 + row16];
    #pragma unroll
    for (int mi = 0; mi < 4; ++mi)
        #pragma unroll
        for (int q = 0; q < 4; ++q) {
            float ps = acc[mi][0][q] * asv0 + acc[mi][1][q] * asv1;
            float pd = acc[mi][0][q] * adv0 + acc[mi][1][q] * adv1;
            #pragma unroll
            for (int o = 1; o < 16; o <<= 1) { ps += __shfl_xor(ps, o); pd += __shfl_xor(pd, o); }
            if (row16 == 0) {
                int rowl = wr * 64 + mi * 16 + kg * 4 + q;
                sRed[rowl * 2 + wc] = ps;
                dRed[rowl * 2 + wc] = pd;
            }
        }
    __syncthreads();
    if (t < 128) {
        sPart[(size_t)blockIdx.y * NTOT + m0 + t] = sRed[t * 2] + sRed[t * 2 + 1];
        dPart[(size_t)blockIdx.y * NTOT + m0 + t] = dRed[t * 2] + dRed[t * 2 + 1];
    }
}

// tiny cross-block reduction: sV/dV = sum of 4 col-block partials
__global__ __launch_bounds__(256) void k_sdsum(const float* __restrict__ sPart, const float* __restrict__ dPart,
                                               float* __restrict__ sV, float* __restrict__ dV) {
    int r = blockIdx.x * 256 + threadIdx.x;
    sV[r] = sPart[r] + sPart[NTOT + r] + sPart[2 * NTOT + r] + sPart[3 * NTOT + r];
    dV[r] = dPart[r] + dPart[NTOT + r] + dPart[2 * NTOT + r] + dPart[3 * NTOT + r];
}

// edge softmax + aggregate: lane-parallel scoring, 8-deep pipelined row gather
__global__ __launch_bounds__(256) void k_agg(const unsigned short* __restrict__ hwB,
                                             const float* __restrict__ sV, const float* __restrict__ dV,
                                             const int* __restrict__ off, const int* __restrict__ csr,
                                             const float* __restrict__ bias,
                                             unsigned short* __restrict__ hout) {
    int tid = threadIdx.x;
    int wave = tid >> 6, lane = tid & 63;
    int node = blockIdx.x * 4 + wave;
    int beg = off[node], end = off[node + 1];
    float di = dV[node];
    const ushort4* hw4 = (const ushort4*)hwB;
    float denom = 0.f;
    float a0 = 0.f, a1 = 0.f, a2 = 0.f, a3 = 0.f;

    for (int cbeg = beg; cbeg < end; cbeg += 64) {
        int j = cbeg + lane;
        int sj = 0;
        float myw = 0.f;
        if (j < end) {
            sj = csr[j];
            float e = sV[sj] + di;
            e = e > 0.f ? e : SLOPE * e;
            myw = __expf(e);
        }
        float csum = myw;
        #pragma unroll
        for (int o = 1; o < 64; o <<= 1) csum += __shfl_xor(csum, o);
        denom += csum;
        int cnt = end - cbeg; if (cnt > 64) cnt = 64;
        int q = 0;
        for (; q + 8 <= cnt; q += 8) {
            int si[8]; float wi[8]; ushort4 vv[8];
            #pragma unroll
            for (int u = 0; u < 8; ++u) {
                si[u] = __builtin_amdgcn_readlane(sj, q + u);
                wi[u] = rlanef(myw, q + u);
            }
            #pragma unroll
            for (int u = 0; u < 8; ++u) vv[u] = hw4[(size_t)si[u] * 64 + lane];
            #pragma unroll
            for (int u = 0; u < 8; ++u) {
                a0 = fmaf(wi[u], b2f(vv[u].x), a0);
                a1 = fmaf(wi[u], b2f(vv[u].y), a1);
                a2 = fmaf(wi[u], b2f(vv[u].z), a2);
                a3 = fmaf(wi[u], b2f(vv[u].w), a3);
            }
        }
        if (q < cnt) {
            int rem = cnt - q;  // 1..7
            int si[8]; float wi[8]; ushort4 vv[8];
            #pragma unroll
            for (int u = 0; u < 8; ++u) {
                int qq = q + (u < rem ? u : 0);
                si[u] = __builtin_amdgcn_readlane(sj, qq);
                wi[u] = (u < rem) ? rlanef(myw, qq) : 0.f;
            }
            #pragma unroll
            for (int u = 0; u < 8; ++u) vv[u] = hw4[(size_t)si[u] * 64 + lane];
            #pragma unroll
            for (int u = 0; u < 8; ++u) {
                a0 = fmaf(wi[u], b2f(vv[u].x), a0);
                a1 = fmaf(wi[u], b2f(vv[u].y), a1);
                a2 = fmaf(wi[u], b2f(vv[u].z), a2);
                a3 = fmaf(wi[u], b2f(vv[u].w), a3);
            }
        }
    }
    float inv = 1.f / denom;
    float4 bb = ((const float4*)bias)[lane];
    ushort4 o;
    float o0 = a0 * inv + bb.x; o.x = f2b(o0 > 0.f ? o0 : 0.f);
    float o1 = a1 * inv + bb.y; o.y = f2b(o1 > 0.f ? o1 : 0.f);
    float o2 = a2 * inv + bb.z; o.z = f2b(o2 > 0.f ? o2 : 0.f);
    float o3 = a3 * inv + bb.w; o.w = f2b(o3 > 0.f ? o3 : 0.f);
    ((ushort4*)hout)[(size_t)node * 64 + lane] = o;
}

// final conv at n==0 (taps 1,2 on nodes 0,1) + LayerNorm + relu
__global__ __launch_bounds__(256) void k_final(const unsigned short* __restrict__ hAb,
                                               const float* __restrict__ wT,
                                               const float* __restrict__ tcb, const float* __restrict__ g,
                                               const float* __restrict__ bln, float* __restrict__ out) {
    __shared__ float r0[HDIM], r1[HDIM];
    __shared__ float red[16];
    int b = blockIdx.x, c = threadIdx.x;
    r0[c] = b2f(hAb[(size_t)(b * NSEQ + 0) * HDIM + c]);
    r1[c] = b2f(hAb[(size_t)(b * NSEQ + 1) * HDIM + c]);
    __syncthreads();
    float a = tcb[c];
    for (int f = 0; f < FDIM; ++f) {
        a = fmaf(wT[(1 * FDIM + f) * HDIM + c], r0[f], a);
        a = fmaf(wT[(2 * FDIM + f) * HDIM + c], r1[f], a);
    }
    float ss = a, sq = a * a;
    #pragma unroll
    for (int o = 1; o < 64; o <<= 1) { ss += __shfl_xor(ss, o); sq += __shfl_xor(sq, o); }
    int wave = c >> 6, lane = c & 63;
    if (lane == 0) { red[wave] = ss; red[8 + wave] = sq; }
    __syncthreads();
    float tot = 0.f, totq = 0.f;
    #pragma unroll
    for (int w = 0; w < 4; ++w) { tot += red[w]; totq += red[8 + w]; }
    float mu = tot * (1.f / HDIM);
    float var = totq * (1.f / HDIM) - mu * mu;
    float v = (a - mu) * rsqrtf(var + LN_EPS) * g[c] + bln[c];
    out[b * HDIM + c] = v > 0.f ? v : 0.f;
}

extern "C" void kernel_launch(void* const* d_in, const int* in_sizes, int n_in,
                              void* d_out, int out_size, void* d_ws, size_t ws_size,
                              hipStream_t stream) {
    const float* x     = (const float*)d_in[0];
    const int*   ei    = (const int*)d_in[1];
    const float* tcw   = (const float*)d_in[2];
    const float* tcb   = (const float*)d_in[3];
    const float* gatW  = (const float*)d_in[4];
    const float* gatas = (const float*)d_in[5];
    const float* gatad = (const float*)d_in[6];
    const float* gatb  = (const float*)d_in[7];
    const float* lng   = (const float*)d_in[8];
    const float* lnb   = (const float*)d_in[9];
    float* out = (float*)d_out;

    char* ws = (char*)d_ws;
    unsigned short* hAb = (unsigned short*)(ws + OFF_HA);
    unsigned short* hwB = (unsigned short*)(ws + OFF_HW);
    unsigned short* xbf = (unsigned short*)(ws + OFF_XB);
    unsigned short* wcB = (unsigned short*)(ws + OFF_WC);
    unsigned short* WTb = (unsigned short*)(ws + OFF_WL);
    float* sPart = (float*)(ws + OFF_SP);
    float* dPart = (float*)(ws + OFF_DP);
    int*   cnt  = (int*)(ws + OFF_CNT);
    int*   offA = (int*)(ws + OFF_OFF);
    int*   cur  = (int*)(ws + OFF_CUR);
    int*   csr  = (int*)(ws + OFF_CSR);
    float* wT   = (float*)(ws + OFF_WT);
    float* sV   = (float*)(ws + OFF_SV);
    float* dV   = (float*)(ws + OFF_DV);

    k_pre<<<5888, 256, 0, stream>>>(x, xbf, cnt, tcw, gatW, wcB, WTb, wT);
    k_count<<<NEE / 256, 256, 0, stream>>>(ei, cnt);
    k_scan<<<1, 1024, 0, stream>>>(cnt, offA, cur);
    k_scatter<<<NEE / 256, 256, 0, stream>>>(ei, cur, csr);
    k_conv<<<dim3(NTOT / 128, 4), 256, 0, stream>>>(xbf, x, wcB, tcb, hAb);

    for (int l = 0; l < NLAYER; ++l) {
        k_gemm_layer<<<dim3(NTOT / 128, 4), 256, 0, stream>>>(
            hAb, WTb + (size_t)l * 65536, gatas + l * HDIM, gatad + l * HDIM, hwB, sPart, dPart);
        k_sdsum<<<NTOT / 256, 256, 0, stream>>>(sPart, dPart, sV, dV);
        k_agg<<<NTOT / 4, 256, 0, stream>>>(hwB, sV, dV, offA, csr, gatb + l * HDIM, hAb);
    }

    k_final<<<BBATCH, 256, 0, stream>>>(hAb, wT, tcb, lng, lnb, out);
}

// Round 9
// 181.568 us; speedup vs baseline: 1.6859x; 1.0245x over previous
//
#include <hip/hip_runtime.h>
#include <hip/hip_bf16.h>
#include <math.h>

#define NTOT 16384
#define HDIM 256
#define BBATCH 4
#define NSEQ 4096
#define FDIM 256
#define NE 262144
#define NEE (NE + NTOT)
#define NLAYER 3
#define LN_EPS 1e-5f
#define SLOPE 0.2f

typedef __attribute__((ext_vector_type(8))) short bf16x8;
typedef __attribute__((ext_vector_type(4))) float f32x4;

#define LDW 80    // B/LDS row stride bytes (64B payload + 16B pad)
#define SLDW 72   // conv slab row stride bytes (64B payload + 8B pad)

// ---- workspace layout (bytes) ----
#define OFF_HA   0u          // ushort[NTOT*256]  8388608
#define OFF_HW   8388608u    // ushort[NTOT*256]  8388608
#define OFF_XB   16777216u   // ushort[NTOT*256]  8388608
#define OFF_WC   25165824u   // ushort[256*768]   393216
#define OFF_WL   25559040u   // ushort[3*256*256] 393216
#define OFF_SP   25952256u   // float[4*NTOT]     262144
#define OFF_DP   26214400u   // float[4*NTOT]     262144
#define OFF_CNT  26476544u   // int[NTOT]
#define OFF_OFF  26542080u   // int[NTOT+1] (pad 65792)
#define OFF_CUR  26607872u   // int[NTOT]
#define OFF_CSR  26673408u   // int[NEE] 1114112
#define OFF_WT   27787520u   // float[3*256*256]  786432
#define OFF_SV   28573952u   // float[NTOT]       65536
#define OFF_DV   28639488u   // float[NTOT]       65536

static __device__ __forceinline__ unsigned short f2b(float f) {
    __hip_bfloat16 h = __float2bfloat16(f);
    return __builtin_bit_cast(unsigned short, h);
}
static __device__ __forceinline__ float b2f(unsigned short u) {
    __hip_bfloat16 h = __builtin_bit_cast(__hip_bfloat16, u);
    return __bfloat162float(h);
}
static __device__ __forceinline__ float rlanef(float v, int l) {
    return __builtin_bit_cast(float, __builtin_amdgcn_readlane(__builtin_bit_cast(int, v), l));
}

// ---- merged pre-pass: x->bf16 (+zero cnt), weight prep ----
__global__ __launch_bounds__(256) void k_pre(const float* __restrict__ x, unsigned short* __restrict__ xb,
                                             int* __restrict__ cnt,
                                             const float* __restrict__ tcw, const float* __restrict__ gatW,
                                             unsigned short* __restrict__ wcB, unsigned short* __restrict__ WTb,
                                             float* __restrict__ wT) {
    int b = blockIdx.x, t = threadIdx.x;
    if (b < 4096) {
        int i = (b * 256 + t) * 4;
        float4 v = *(const float4*)(x + i);
        ushort4 o;
        o.x = f2b(v.x); o.y = f2b(v.y); o.z = f2b(v.z); o.w = f2b(v.w);
        *(ushort4*)(xb + i) = o;
        if (b < 16) *(int4*)(cnt + i) = make_int4(0, 0, 0, 0);
    } else {
        int bb = b - 4096;
        if (bb < 256) {
            const float* s = tcw + bb * 768 + t * 3;
            wcB[bb * 768 + 0 + t]   = f2b(s[0]);
            wcB[bb * 768 + 256 + t] = f2b(s[1]);
            wcB[bb * 768 + 512 + t] = f2b(s[2]);
        } else if (bb < 1024) {
            int ln = bb - 256; int n = ln & 255; int l = ln >> 8;
            WTb[(size_t)l * 65536 + n * 256 + t] = f2b(gatW[(size_t)l * 65536 + t * 256 + n]);
        } else {
            int fk = bb - 1024; int f = fk / 3, k = fk - 3 * f;
            wT[(k * FDIM + f) * HDIM + t] = tcw[t * 768 + fk];
        }
    }
}

__global__ __launch_bounds__(1024) void k_scan(const int* __restrict__ cnt, int* __restrict__ off,
                                               int* __restrict__ cur) {
    __shared__ int sums[1024];
    int t = threadIdx.x;
    int base = t * 16;
    int c[16]; int s = 0;
    #pragma unroll
    for (int j = 0; j < 16; ++j) { c[j] = cnt[base + j]; s += c[j]; }
    sums[t] = s;
    __syncthreads();
    for (int dstep = 1; dstep < 1024; dstep <<= 1) {
        int v = (t >= dstep) ? sums[t - dstep] : 0;
        __syncthreads();
        sums[t] += v;
        __syncthreads();
    }
    int pre = (t == 0) ? 0 : sums[t - 1];
    #pragma unroll
    for (int j = 0; j < 16; ++j) { off[base + j] = pre; cur[base + j] = pre; pre += c[j]; }
    if (t == 1023) off[NTOT] = pre;
}

// ---------------- conv GEMM (halo slab) + co-dispatched edge COUNT ----------------
// grid (128+272, 4): x<128 -> conv tile (m0=x*128, n0=y*64); x>=128 -> count slice.
// Count depends only on ei/cnt (zeroed in k_pre); overlaps with conv MFMA.
__global__ __launch_bounds__(256) void k_conv(const unsigned short* __restrict__ xbf,
                                              const unsigned short* __restrict__ wcB,
                                              const float* __restrict__ tcb,
                                              unsigned short* __restrict__ hAb,
                                              const int* __restrict__ ei, int* __restrict__ cnt) {
    __shared__ char slab[130 * SLDW];
    __shared__ char Bs[3 * 64 * LDW];
    int t = threadIdx.x;
    if (blockIdx.x >= 128) {   // count part
        int cid = (blockIdx.x - 128) * 4 + blockIdx.y;   // 0..1087
        int e = cid * 256 + t;
        int dst = (e < NE) ? ei[NE + e] : (e - NE);
        atomicAdd(&cnt[dst], 1);
        return;
    }
    int m0 = blockIdx.x * 128, n0 = blockIdx.y * 64;
    int bb = m0 >> 12;
    int nloc0 = m0 & 4095;
    int w = t >> 6, lane = t & 63;
    int wr = w >> 1, wc = w & 1;
    int row16 = lane & 15, kg = lane >> 4;
    int rA = t >> 1, hh = t & 1;
    f32x4 acc[4][2];
    #pragma unroll
    for (int mi = 0; mi < 4; ++mi)
        #pragma unroll
        for (int ni = 0; ni < 2; ++ni) acc[mi][ni] = (f32x4)(0.f);

    for (int kb = 0; kb < 8; ++kb) {
        int c0 = kb * 32;
        __syncthreads();
        {
            int nl = nloc0 - 1 + rA;
            uint4 v0 = make_uint4(0, 0, 0, 0), v1 = make_uint4(0, 0, 0, 0);
            if ((unsigned)nl < 4096u) {
                const uint4* s = (const uint4*)(xbf + ((size_t)(bb << 12) + nl) * 256 + c0 + hh * 16);
                v0 = s[0]; v1 = s[1];
            }
            *(uint4*)&slab[rA * SLDW + hh * 32] = v0;
            *(uint4*)&slab[rA * SLDW + hh * 32 + 16] = v1;
        }
        if (t < 8) {
            int r = 128 + (t >> 2), u = t & 3;
            int nl = nloc0 - 1 + r;
            uint4 v = make_uint4(0, 0, 0, 0);
            if ((unsigned)nl < 4096u)
                v = *(const uint4*)(xbf + ((size_t)(bb << 12) + nl) * 256 + c0 + u * 8);
            *(uint4*)&slab[r * SLDW + u * 16] = v;
        }
        {
            int rB = t >> 2, u = t & 3;
            const unsigned short* wrow = wcB + (size_t)(n0 + rB) * 768 + c0 + u * 8;
            #pragma unroll
            for (int p = 0; p < 3; ++p)
                *(uint4*)&Bs[p * 64 * LDW + rB * LDW + u * 16] = *(const uint4*)(wrow + p * 256);
        }
        __syncthreads();
        #pragma unroll
        for (int p = 0; p < 3; ++p) {
            bf16x8 bfr[2];
            #pragma unroll
            for (int ni = 0; ni < 2; ++ni)
                bfr[ni] = *(bf16x8*)&Bs[p * 64 * LDW + (wc * 32 + ni * 16 + row16) * LDW + kg * 16];
            #pragma unroll
            for (int mi = 0; mi < 4; ++mi) {
                bf16x8 afr = *(bf16x8*)&slab[(wr * 64 + mi * 16 + row16 + p) * SLDW + kg * 16];
                acc[mi][0] = __builtin_amdgcn_mfma_f32_16x16x32_bf16(afr, bfr[0], acc[mi][0], 0, 0, 0);
                acc[mi][1] = __builtin_amdgcn_mfma_f32_16x16x32_bf16(afr, bfr[1], acc[mi][1], 0, 0, 0);
            }
        }
    }
    #pragma unroll
    for (int mi = 0; mi < 4; ++mi)
        #pragma unroll
        for (int ni = 0; ni < 2; ++ni) {
            int rowl = wr * 64 + mi * 16 + kg * 4;
            int coll = wc * 32 + ni * 16 + row16;
            int n = n0 + coll;
            float bc = tcb[n];
            #pragma unroll
            for (int q = 0; q < 4; ++q) {
                size_t node = (size_t)(m0 + rowl + q);
                float v = acc[mi][ni][q] + bc + b2f(xbf[node * 256 + n]);  // bf16 residual (L2-hot)
                v = v > 0.f ? v : 0.f;
                hAb[node * 256 + n] = f2b(v);
            }
        }
}

// ---------------- MFMA GEMM + fused s/d partials + co-dispatched CSR SCATTER (l==0) ----------------
// grid (128+272, 4) when doScat: x>=128 -> scatter slice; else (128, 4).
__global__ __launch_bounds__(256) void k_gemm_layer(const unsigned short* __restrict__ hAb,
                                                    const unsigned short* __restrict__ WT,
                                                    const float* __restrict__ as, const float* __restrict__ ad,
                                                    unsigned short* __restrict__ hwB,
                                                    float* __restrict__ sPart, float* __restrict__ dPart,
                                                    const int* __restrict__ ei, int* __restrict__ cur,
                                                    int* __restrict__ csr) {
    __shared__ char lds[128 * LDW + 64 * LDW];
    __shared__ float sRed[256], dRed[256];
    char* As = lds;
    char* Bs = lds + 128 * LDW;
    int t = threadIdx.x;
    if (blockIdx.x >= 128) {   // scatter part (only dispatched for l==0)
        int cid = (blockIdx.x - 128) * 4 + blockIdx.y;   // 0..1087
        int e = cid * 256 + t;
        int src, dst;
        if (e < NE) { src = ei[e]; dst = ei[NE + e]; } else { src = dst = e - NE; }
        int pos = atomicAdd(&cur[dst], 1);
        csr[pos] = src;
        return;
    }
    int m0 = blockIdx.x * 128, n0 = blockIdx.y * 64;
    int w = t >> 6, lane = t & 63;
    int wr = w >> 1, wc = w & 1;
    int row16 = lane & 15, kg = lane >> 4;
    int rA = t >> 1, hh = t & 1;
    f32x4 acc[4][2];
    #pragma unroll
    for (int mi = 0; mi < 4; ++mi)
        #pragma unroll
        for (int ni = 0; ni < 2; ++ni) acc[mi][ni] = (f32x4)(0.f);

    for (int kb = 0; kb < 256; kb += 32) {
        {
            const uint4* src = (const uint4*)(hAb + (size_t)(m0 + rA) * 256 + kb + hh * 16);
            uint4 v0 = src[0], v1 = src[1];
            *(uint4*)&As[rA * LDW + hh * 32] = v0;
            *(uint4*)&As[rA * LDW + hh * 32 + 16] = v1;
        }
        if (t < 128) {
            int rB = t >> 1;
            const uint4* src = (const uint4*)(WT + (size_t)(n0 + rB) * 256 + kb + hh * 16);
            uint4 v0 = src[0], v1 = src[1];
            *(uint4*)&Bs[rB * LDW + hh * 32] = v0;
            *(uint4*)&Bs[rB * LDW + hh * 32 + 16] = v1;
        }
        __syncthreads();
        bf16x8 bfr[2];
        #pragma unroll
        for (int ni = 0; ni < 2; ++ni)
            bfr[ni] = *(bf16x8*)&Bs[(wc * 32 + ni * 16 + row16) * LDW + kg * 16];
        #pragma unroll
        for (int mi = 0; mi < 4; ++mi) {
            bf16x8 afr = *(bf16x8*)&As[(wr * 64 + mi * 16 + row16) * LDW + kg * 16];
            acc[mi][0] = __builtin_amdgcn_mfma_f32_16x16x32_bf16(afr, bfr[0], acc[mi][0], 0, 0, 0);
            acc[mi][1] = __builtin_amdgcn_mfma_f32_16x16x32_bf16(afr, bfr[1], acc[mi][1], 0, 0, 0);
        }
        __syncthreads();
    }
    #pragma unroll
    for (int mi = 0; mi < 4; ++mi)
        #pragma unroll
        for (int ni = 0; ni < 2; ++ni) {
            int rowl = wr * 64 + mi * 16 + kg * 4;
            int coll = wc * 32 + ni * 16 + row16;
            size_t base = (size_t)(m0 + rowl) * 256 + n0 + coll;
            #pragma unroll
            for (int q = 0; q < 4; ++q) hwB[base + (size_t)q * 256] = f2b(acc[mi][ni][q]);
        }
    float asv0 = as[n0 + wc * 32 + row16];
    float asv1 = as[n0 + wc * 32 + 16 + row16];
    float adv0 = ad[n0 + wc * 32 + row16];
    float adv1 = ad[n0 + wc * 32 + 16 + row16];
    #pragma unroll
    for (int mi = 0; mi < 4; ++mi)
        #pragma unroll
        for (int q = 0; q < 4; ++q) {
            float ps = acc[mi][0][q] * asv0 + acc[mi][1][q] * asv1;
            float pd = acc[mi][0][q] * adv0 + acc[mi][1][q] * adv1;
            #pragma unroll
            for (int o = 1; o < 16; o <<= 1) { ps += __shfl_xor(ps, o); pd += __shfl_xor(pd, o); }
            if (row16 == 0) {
                int rowl = wr * 64 + mi * 16 + kg * 4 + q;
                sRed[rowl * 2 + wc] = ps;
                dRed[rowl * 2 + wc] = pd;
            }
        }
    __syncthreads();
    if (t < 128) {
        sPart[(size_t)blockIdx.y * NTOT + m0 + t] = sRed[t * 2] + sRed[t * 2 + 1];
        dPart[(size_t)blockIdx.y * NTOT + m0 + t] = dRed[t * 2] + dRed[t * 2 + 1];
    }
}

__global__ __launch_bounds__(256) void k_sdsum(const float* __restrict__ sPart, const float* __restrict__ dPart,
                                               float* __restrict__ sV, float* __restrict__ dV) {
    int r = blockIdx.x * 256 + threadIdx.x;
    sV[r] = sPart[r] + sPart[NTOT + r] + sPart[2 * NTOT + r] + sPart[3 * NTOT + r];
    dV[r] = dPart[r] + dPart[NTOT + r] + dPart[2 * NTOT + r] + dPart[3 * NTOT + r];
}

// edge softmax + aggregate: lane-parallel scoring, 8-deep pipelined row gather
__global__ __launch_bounds__(256) void k_agg(const unsigned short* __restrict__ hwB,
                                             const float* __restrict__ sV, const float* __restrict__ dV,
                                             const int* __restrict__ off, const int* __restrict__ csr,
                                             const float* __restrict__ bias,
                                             unsigned short* __restrict__ hout) {
    int tid = threadIdx.x;
    int wave = tid >> 6, lane = tid & 63;
    int node = blockIdx.x * 4 + wave;
    int beg = off[node], end = off[node + 1];
    float di = dV[node];
    const ushort4* hw4 = (const ushort4*)hwB;
    float denom = 0.f;
    float a0 = 0.f, a1 = 0.f, a2 = 0.f, a3 = 0.f;

    for (int cbeg = beg; cbeg < end; cbeg += 64) {
        int j = cbeg + lane;
        int sj = 0;
        float myw = 0.f;
        if (j < end) {
            sj = csr[j];
            float e = sV[sj] + di;
            e = e > 0.f ? e : SLOPE * e;
            myw = __expf(e);
        }
        float csum = myw;
        #pragma unroll
        for (int o = 1; o < 64; o <<= 1) csum += __shfl_xor(csum, o);
        denom += csum;
        int cnt = end - cbeg; if (cnt > 64) cnt = 64;
        int q = 0;
        for (; q + 8 <= cnt; q += 8) {
            int si[8]; float wi[8]; ushort4 vv[8];
            #pragma unroll
            for (int u = 0; u < 8; ++u) {
                si[u] = __builtin_amdgcn_readlane(sj, q + u);
                wi[u] = rlanef(myw, q + u);
            }
            #pragma unroll
            for (int u = 0; u < 8; ++u) vv[u] = hw4[(size_t)si[u] * 64 + lane];
            #pragma unroll
            for (int u = 0; u < 8; ++u) {
                a0 = fmaf(wi[u], b2f(vv[u].x), a0);
                a1 = fmaf(wi[u], b2f(vv[u].y), a1);
                a2 = fmaf(wi[u], b2f(vv[u].z), a2);
                a3 = fmaf(wi[u], b2f(vv[u].w), a3);
            }
        }
        if (q < cnt) {
            int rem = cnt - q;
            int si[8]; float wi[8]; ushort4 vv[8];
            #pragma unroll
            for (int u = 0; u < 8; ++u) {
                int qq = q + (u < rem ? u : 0);
                si[u] = __builtin_amdgcn_readlane(sj, qq);
                wi[u] = (u < rem) ? rlanef(myw, qq) : 0.f;
            }
            #pragma unroll
            for (int u = 0; u < 8; ++u) vv[u] = hw4[(size_t)si[u] * 64 + lane];
            #pragma unroll
            for (int u = 0; u < 8; ++u) {
                a0 = fmaf(wi[u], b2f(vv[u].x), a0);
                a1 = fmaf(wi[u], b2f(vv[u].y), a1);
                a2 = fmaf(wi[u], b2f(vv[u].z), a2);
                a3 = fmaf(wi[u], b2f(vv[u].w), a3);
            }
        }
    }
    float inv = 1.f / denom;
    float4 bb = ((const float4*)bias)[lane];
    ushort4 o;
    float o0 = a0 * inv + bb.x; o.x = f2b(o0 > 0.f ? o0 : 0.f);
    float o1 = a1 * inv + bb.y; o.y = f2b(o1 > 0.f ? o1 : 0.f);
    float o2 = a2 * inv + bb.z; o.z = f2b(o2 > 0.f ? o2 : 0.f);
    float o3 = a3 * inv + bb.w; o.w = f2b(o3 > 0.f ? o3 : 0.f);
    ((ushort4*)hout)[(size_t)node * 64 + lane] = o;
}

// final conv at n==0 + LayerNorm + relu
__global__ __launch_bounds__(256) void k_final(const unsigned short* __restrict__ hAb,
                                               const float* __restrict__ wT,
                                               const float* __restrict__ tcb, const float* __restrict__ g,
                                               const float* __restrict__ bln, float* __restrict__ out) {
    __shared__ float r0[HDIM], r1[HDIM];
    __shared__ float red[16];
    int b = blockIdx.x, c = threadIdx.x;
    r0[c] = b2f(hAb[(size_t)(b * NSEQ + 0) * HDIM + c]);
    r1[c] = b2f(hAb[(size_t)(b * NSEQ + 1) * HDIM + c]);
    __syncthreads();
    float a = tcb[c];
    for (int f = 0; f < FDIM; ++f) {
        a = fmaf(wT[(1 * FDIM + f) * HDIM + c], r0[f], a);
        a = fmaf(wT[(2 * FDIM + f) * HDIM + c], r1[f], a);
    }
    float ss = a, sq = a * a;
    #pragma unroll
    for (int o = 1; o < 64; o <<= 1) { ss += __shfl_xor(ss, o); sq += __shfl_xor(sq, o); }
    int wave = c >> 6, lane = c & 63;
    if (lane == 0) { red[wave] = ss; red[8 + wave] = sq; }
    __syncthreads();
    float tot = 0.f, totq = 0.f;
    #pragma unroll
    for (int w = 0; w < 4; ++w) { tot += red[w]; totq += red[8 + w]; }
    float mu = tot * (1.f / HDIM);
    float var = totq * (1.f / HDIM) - mu * mu;
    float v = (a - mu) * rsqrtf(var + LN_EPS) * g[c] + bln[c];
    out[b * HDIM + c] = v > 0.f ? v : 0.f;
}

extern "C" void kernel_launch(void* const* d_in, const int* in_sizes, int n_in,
                              void* d_out, int out_size, void* d_ws, size_t ws_size,
                              hipStream_t stream) {
    const float* x     = (const float*)d_in[0];
    const int*   ei    = (const int*)d_in[1];
    const float* tcw   = (const float*)d_in[2];
    const float* tcb   = (const float*)d_in[3];
    const float* gatW  = (const float*)d_in[4];
    const float* gatas = (const float*)d_in[5];
    const float* gatad = (const float*)d_in[6];
    const float* gatb  = (const float*)d_in[7];
    const float* lng   = (const float*)d_in[8];
    const float* lnb   = (const float*)d_in[9];
    float* out = (float*)d_out;

    char* ws = (char*)d_ws;
    unsigned short* hAb = (unsigned short*)(ws + OFF_HA);
    unsigned short* hwB = (unsigned short*)(ws + OFF_HW);
    unsigned short* xbf = (unsigned short*)(ws + OFF_XB);
    unsigned short* wcB = (unsigned short*)(ws + OFF_WC);
    unsigned short* WTb = (unsigned short*)(ws + OFF_WL);
    float* sPart = (float*)(ws + OFF_SP);
    float* dPart = (float*)(ws + OFF_DP);
    int*   cnt  = (int*)(ws + OFF_CNT);
    int*   offA = (int*)(ws + OFF_OFF);
    int*   cur  = (int*)(ws + OFF_CUR);
    int*   csr  = (int*)(ws + OFF_CSR);
    float* wT   = (float*)(ws + OFF_WT);
    float* sV   = (float*)(ws + OFF_SV);
    float* dV   = (float*)(ws + OFF_DV);

    k_pre<<<5888, 256, 0, stream>>>(x, xbf, cnt, tcw, gatW, wcB, WTb, wT);
    // conv tiles + co-dispatched count (count needs cnt zeroed by k_pre: stream-ordered)
    k_conv<<<dim3(128 + 272, 4), 256, 0, stream>>>(xbf, wcB, tcb, hAb, ei, cnt);
    k_scan<<<1, 1024, 0, stream>>>(cnt, offA, cur);

    for (int l = 0; l < NLAYER; ++l) {
        // l==0: extra 272x4 blocks perform the CSR scatter (needs cur from k_scan),
        // overlapping with the GEMM; agg (which needs csr) launches after.
        dim3 grid(l == 0 ? 128 + 272 : 128, 4);
        k_gemm_layer<<<grid, 256, 0, stream>>>(
            hAb, WTb + (size_t)l * 65536, gatas + l * HDIM, gatad + l * HDIM,
            hwB, sPart, dPart, ei, cur, csr);
        k_sdsum<<<NTOT / 256, 256, 0, stream>>>(sPart, dPart, sV, dV);
        k_agg<<<NTOT / 4, 256, 0, stream>>>(hwB, sV, dV, offA, csr, gatb + l * HDIM, hAb);
    }

    k_final<<<BBATCH, 256, 0, stream>>>(hAb, wT, tcb, lng, lnb, out);
}